// Round 12
// baseline (104.158 us; speedup 1.0000x reference)
//
#include <hip/hip_runtime.h>
#include <hip/hip_bf16.h>

#define NSEQ   192
#define PADV   -1000.0f
#define NEGINF -1.0e30f

typedef _Float16 f16x8 __attribute__((ext_vector_type(8)));
typedef float    f32x4 __attribute__((ext_vector_type(4)));

__device__ __forceinline__ void glds16(const void* g, void* l) {
  __builtin_amdgcn_global_load_lds(
      (const __attribute__((address_space(1))) unsigned int*)g,
      (__attribute__((address_space(3))) unsigned int*)l, 16, 0, 0);
}

#define MFMA16(a, b, c) __builtin_amdgcn_mfma_f32_16x16x32_f16((a), (b), (c), 0, 0, 0)

// ---------------------------------------------------------------------------
// prep_pack: repack weights into f16 MFMA fragment order (frag: lane l elem e
// holds M[k=(l>>4)*8+e][h=(l&15)+16q]); W1c/W2 as 12-frag padded slices for
// uniform 3-frag/wave staging. Also zeroes A12 and pads b1 -> b1p[160] f32.
// ---------------------------------------------------------------------------
__global__ __launch_bounds__(256) void prep_pack(const float* __restrict__ W1,
                                                 const float* __restrict__ W2,
                                                 const float* __restrict__ b1,
                                                 _Float16* __restrict__ W1abp,
                                                 _Float16* __restrict__ W1cp,
                                                 _Float16* __restrict__ W2p,
                                                 float* __restrict__ b1p,
                                                 float* __restrict__ A12) {
  int idx = blockIdx.x * 256 + threadIdx.x;   // grid 1657*256 = 424192
  if (idx < 245760) { A12[idx] = 0.f; A12[245760 + idx] = 0.f; }

  if (idx < 245760) {                         // W1ab: 24 kk x 20 frags
    int e = idx & 7, l = (idx >> 3) & 63, t = idx >> 9;
    int ct = t % 20, kk = t / 20;
    int k = kk * 32 + ((l >> 4) << 3) + e;    // 0..767
    int hp = ct * 16 + (l & 15);              // 0..319
    int col = (hp < 160) ? hp : hp - 160;
    int rbase = (hp < 160) ? 0 : 768;
    float v = (col < 150) ? W1[(size_t)(rbase + k) * 150 + col] : 0.f;
    W1abp[idx] = (_Float16)v;
  } else if (idx < 393216) {                  // W1c: 24 kk x 12 frags (pad 2)
    int j = idx - 245760;
    int kk = j / 6144, rem = j % 6144;
    int q = rem >> 9, l = (rem >> 3) & 63, e = rem & 7;
    int k = kk * 32 + ((l >> 4) << 3) + e;
    int h = q * 16 + (l & 15);
    float v = (q < 10 && h < 150) ? W1[(size_t)(1536 + k) * 150 + h] : 0.f;
    W1cp[j] = (_Float16)v;
  } else if (idx < 423936) {                  // W2: 5 s x 12 frags (pad 2)
    int j = idx - 393216;
    int s = j / 6144, rem = j % 6144;
    int q = rem >> 9, l = (rem >> 3) & 63, e = rem & 7;
    int k = s * 32 + ((l >> 4) << 3) + e;
    int h = q * 16 + (l & 15);
    float v = (q < 10 && k < 150 && h < 150) ? W2[(size_t)k * 150 + h] : 0.f;
    W2p[j] = (_Float16)v;
  } else if (idx < 424096) {
    int h = idx - 423936;
    b1p[h] = (h < 150) ? b1[h] : 0.f;
  }
}

// ---------------------------------------------------------------------------
// prep_gemm: A12[1536][320] += E @ [W1a|W1b], K split 8 ways (f32 atomics).
// ---------------------------------------------------------------------------
__global__ __launch_bounds__(256) void prep_gemm(const float* __restrict__ E,
                                                 const _Float16* __restrict__ W1abp,
                                                 float* __restrict__ A12) {
  int tid = threadIdx.x;
  int w = tid >> 6, l = tid & 63, m = l & 15, kg = l >> 4;
  int mt = blockIdx.x >> 3;                   // 0..95
  int c  = blockIdx.x & 7;                    // K-chunk 0..7
  const float* ep = E + (size_t)(mt * 16 + m) * 768 + c * 96;

  f32x4 acc[5];
#pragma unroll
  for (int u = 0; u < 5; ++u) acc[u] = (f32x4){0.f, 0.f, 0.f, 0.f};

#pragma unroll
  for (int kk = 0; kk < 3; ++kk) {
    int k = kk * 32 + kg * 8;
    f32x4 x0 = *(const f32x4*)(ep + k);
    f32x4 x1 = *(const f32x4*)(ep + k + 4);
    f16x8 af;
#pragma unroll
    for (int e = 0; e < 4; ++e) { af[e] = (_Float16)x0[e]; af[e + 4] = (_Float16)x1[e]; }
    const f16x8* wp = (const f16x8*)W1abp + (size_t)(((c * 3 + kk) * 20) + w * 5) * 64 + l;
#pragma unroll
    for (int u = 0; u < 5; ++u)
      acc[u] = MFMA16(af, wp[u * 64], acc[u]);
  }
#pragma unroll
  for (int u = 0; u < 5; ++u)
#pragma unroll
    for (int r = 0; r < 4; ++r)
      atomicAdd(&A12[(size_t)(mt * 16 + kg * 4 + r) * 320 + (w * 5 + u) * 16 + m], acc[u][r]);
}

// ---------------------------------------------------------------------------
// pair_mlp r12: identical to r11 EXCEPT no min-waves clamp in launch_bounds
// (r11's (256,2) capped VGPR at 128 and spilled ~33 MB/dispatch to scratch;
// WRITE_SIZE 594 KB -> 23.4 MB was the smoking gun). LDS 75 KB still gives
// 2 blocks/CU; VGPR ~200-240 <= 256 keeps 2 waves/SIMD.
// ---------------------------------------------------------------------------
__global__ __launch_bounds__(256) void pair_mlp(
    const float* __restrict__ E, const float* __restrict__ A12,
    const _Float16* __restrict__ W1cp, const _Float16* __restrict__ W2p,
    const float* __restrict__ b1p, const float* __restrict__ b2,
    const float* __restrict__ W3, const float* __restrict__ b3,
    float* __restrict__ out) {
  __shared__ alignas(16) char pool[75008];
  // [0,24576)      W slab dbuf: 2 x 12 frags x 1024B
  // [24576,49152)  eib 16 rows x 96 chunks(16B), XOR-swizzled  | phase2: h1
  // [49152,73728)  ejb 16 rows x 96 chunks(16B), XOR-swizzled  | slots 8x6144
  // [73728,75008)  bw: b2f[160], w3f[160] f32
  char* eib = pool + 24576;
  char* ejb = pool + 49152;

  const int tid = threadIdx.x;
  const int w = tid >> 6, l = tid & 63;
  const int m = l & 15, kg = l >> 4;

  // XCD-aware bijective swizzle (624 == 8*78), tri decode (16x16 tiles)
  int bid = blockIdx.x;
  int blk = (bid & 7) * 78 + (bid >> 3);
  int b = blk / 78, r0 = blk - b * 78;
  int it = (int)((sqrtf(8.f * (float)r0 + 1.f) - 1.f) * 0.5f);
  while (it * (it + 1) / 2 > r0) --it;
  while ((it + 1) * (it + 2) / 2 <= r0) ++it;
  int jt = r0 - it * (it + 1) / 2;            // 0..it

  const int ibase = b * NSEQ + it * 16;
  const int jbase = b * NSEQ + jt * 16;

  // ---- stage W1c slice 0 (3 frags/wave) into buf0 ----
#pragma unroll
  for (int q = 0; q < 3; ++q)
    glds16(W1cp + (size_t)(w * 3 + q) * 512 + l * 8, pool + (w * 3 + q) * 1024);

  // ---- stage e_i + e_j as f16, chunk-XOR swizzled ----
#pragma unroll
  for (int q = 0; q < 12; ++q) {
    int t = tid + 256 * q;                    // 0..3071
    int isI = (t < 1536);
    int tt = isI ? t : t - 1536;
    int r = tt / 96, d = tt - (tt / 96) * 96;
    int sc = d ^ (r & 7);
    const float* src = E + (size_t)((isI ? ibase : jbase) + r) * 768 + sc * 8;
    f32x4 a0 = *(const f32x4*)(src);
    f32x4 a1 = *(const f32x4*)(src + 4);
    f16x8 v;
#pragma unroll
    for (int e = 0; e < 4; ++e) { v[e] = (_Float16)a0[e]; v[e + 4] = (_Float16)a1[e]; }
    *(f16x8*)((isI ? eib : ejb) + r * 1536 + d * 16) = v;
  }

  // ---- stage b2/W3 (padded) ----
  if (tid < 160) {
    float* bwf = (float*)(pool + 73728);
    bwf[tid]       = (tid < 150) ? b2[tid] : 0.f;
    bwf[160 + tid] = (tid < 150) ? W3[tid] : 0.f;
  }
  float b3v = b3[0];

  // ---- acc1 init: C1[h = ct*16+kg*4+r][i = m] = A1[i][h]+A2[j][h]+b1[h] ----
  f32x4 acc1[10][4];
#pragma unroll
  for (int ct = 0; ct < 10; ++ct) {
    f32x4 a1v = *(const f32x4*)(A12 + (size_t)(ibase + m) * 320 + ct * 16 + kg * 4);
    f32x4 b1v = *(const f32x4*)(b1p + ct * 16 + kg * 4);
#pragma unroll
    for (int pt = 0; pt < 4; ++pt) {
      f32x4 a2v = *(const f32x4*)(A12 + (size_t)(jbase + w * 4 + pt) * 320 + 160 + ct * 16 + kg * 4);
      acc1[ct][pt] = a1v + a2v + b1v;
    }
  }

  __syncthreads();   // one full drain: slice0 + e-stage + bw resident

  // ---- GEMM1: 24 K=32 rounds; dbuf slabs, counted vmcnt, 2 barriers ----
  for (int t = 0; t < 24; ++t) {
    if (t < 23) {
#pragma unroll
      for (int q = 0; q < 3; ++q)
        glds16(W1cp + ((size_t)(t + 1) * 12 + w * 3 + q) * 512 + l * 8,
               pool + ((t + 1) & 1) * 12288 + (w * 3 + q) * 1024);
      asm volatile("s_waitcnt vmcnt(3)" ::: "memory");
    } else {
      asm volatile("s_waitcnt vmcnt(0)" ::: "memory");
    }
    __builtin_amdgcn_s_barrier();

    const char* wb = pool + (t & 1) * 12288;
    int cb = t * 4 + kg;
    f16x8 eiv = *(const f16x8*)(eib + m * 1536 + ((cb ^ (m & 7)) << 4));
    f16x8 pf[4];
#pragma unroll
    for (int pt = 0; pt < 4; ++pt) {
      int jr = w * 4 + pt;
      f16x8 ejv = *(const f16x8*)(ejb + jr * 1536 + ((cb ^ (jr & 7)) << 4));
      pf[pt] = eiv * ejv;                     // v_pk_mul_f16 x4, no cvts
    }
#pragma unroll
    for (int ct = 0; ct < 10; ++ct) {
      f16x8 wf = *(const f16x8*)(wb + ct * 1024 + l * 16);
#pragma unroll
      for (int pt = 0; pt < 4; ++pt)
        acc1[ct][pt] = MFMA16(wf, pf[pt], acc1[ct][pt]);
    }
    __builtin_amdgcn_s_barrier();
  }

  // ---- GEMM2 setup: stage W2 slice 0; write h1 pass 0 into dead e-region --
  auto write_h1 = [&](int c, int pt) {
    char* hbp = eib + (w * 2 + c) * 6144;     // slot (w,c): 16 rows x 384B
#pragma unroll
    for (int ct = 0; ct < 10; ++ct) {
      union { _Float16 h[4]; unsigned u[2]; } cv;
      cv.h[0] = (_Float16)fmaxf(acc1[ct][pt][0], 0.f);
      cv.h[1] = (_Float16)fmaxf(acc1[ct][pt][1], 0.f);
      cv.h[2] = (_Float16)fmaxf(acc1[ct][pt][2], 0.f);
      cv.h[3] = (_Float16)fmaxf(acc1[ct][pt][3], 0.f);
      int cc = (2 * ct + (kg >> 1)) ^ (m & 7);
      char* dst = hbp + m * 384 + cc * 16 + (kg & 1) * 8;
      *(unsigned*)(dst)     = cv.u[0];
      *(unsigned*)(dst + 4) = cv.u[1];
    }
  };

#pragma unroll
  for (int q = 0; q < 3; ++q)
    glds16(W2p + (size_t)(w * 3 + q) * 512 + l * 8, pool + (w * 3 + q) * 1024);
  write_h1(0, 0);
  write_h1(1, 1);

  f32x4 acc2[10][2];
  float sums[2][2];

  // ---- GEMM2: 10 rounds = 2 passes x 5 slices ----
#pragma unroll
  for (int r = 0; r < 10; ++r) {
    const int p = r / 5, s = r - p * 5;
    if (r < 9) {
      int ns = (r + 1 >= 5) ? r + 1 - 5 : r + 1;
#pragma unroll
      for (int q = 0; q < 3; ++q)
        glds16(W2p + ((size_t)ns * 12 + w * 3 + q) * 512 + l * 8,
               pool + ((r + 1) & 1) * 12288 + (w * 3 + q) * 1024);
      asm volatile("s_waitcnt vmcnt(3)" ::: "memory");
    } else {
      asm volatile("s_waitcnt vmcnt(0)" ::: "memory");
    }
    __builtin_amdgcn_s_barrier();

    if (r == 5) { write_h1(0, 2); write_h1(1, 3); }
    if (s == 0) {
#pragma unroll
      for (int ct = 0; ct < 10; ++ct) {
        acc2[ct][0] = (f32x4){0.f, 0.f, 0.f, 0.f};
        acc2[ct][1] = (f32x4){0.f, 0.f, 0.f, 0.f};
      }
    }

    const char* wb = pool + (r & 1) * 12288;
    f16x8 hf[2];
#pragma unroll
    for (int c = 0; c < 2; ++c)
      hf[c] = *(const f16x8*)(eib + (w * 2 + c) * 6144 + m * 384 +
                              (((4 * s + kg) ^ (m & 7)) << 4));
#pragma unroll
    for (int ct = 0; ct < 10; ++ct) {
      f16x8 wf = *(const f16x8*)(wb + ct * 1024 + l * 16);
      acc2[ct][0] = MFMA16(wf, hf[0], acc2[ct][0]);
      acc2[ct][1] = MFMA16(wf, hf[1], acc2[ct][1]);
    }

    if (s == 4) {   // pass epilogue: fold + cross-kg reduce (stores deferred)
      const float* bwp = (const float*)(pool + 73728);
#pragma unroll
      for (int c = 0; c < 2; ++c) {
        float sum = 0.f;
#pragma unroll
        for (int ct = 0; ct < 10; ++ct) {
          f32x4 b2q = *(const f32x4*)(bwp + ct * 16 + kg * 4);
          f32x4 w3q = *(const f32x4*)(bwp + 160 + ct * 16 + kg * 4);
#pragma unroll
          for (int r2 = 0; r2 < 4; ++r2)
            sum += fmaxf(acc2[ct][c][r2] + b2q[r2], 0.f) * w3q[r2];
        }
        sum += __shfl_xor(sum, 16, 64);
        sum += __shfl_xor(sum, 32, 64);
        sums[p][c] = sum;
      }
    }
    __builtin_amdgcn_s_barrier();
  }

  // ---- deferred stores ----
  if (kg == 0) {
    int il = it * 16 + m;
#pragma unroll
    for (int p = 0; p < 2; ++p)
#pragma unroll
      for (int c = 0; c < 2; ++c) {
        int jl = jt * 16 + w * 4 + p * 2 + c;
        if (jl < il)
          out[(size_t)(b * NSEQ + il) * NSEQ + jl] = sums[p][c] + b3v;
      }
  }
}

// ---------------------------------------------------------------------------
// softmax: 4 (b,i)-rows per block, one wave each.
// ---------------------------------------------------------------------------
__global__ __launch_bounds__(256) void softmax_rows(float* __restrict__ out) {
  int w = threadIdx.x >> 6, l = threadIdx.x & 63;
  int blk = blockIdx.x * 4 + w;   // 0..1535 = b*192+i
  int i = blk % NSEQ;
  size_t base = (size_t)blk * NSEQ;
  float v[3];
  float mx = NEGINF;
#pragma unroll
  for (int t = 0; t < 3; ++t) {
    int j = l + 64 * t;
    float x = (j < i) ? out[base + j] : (j == i ? 0.f : NEGINF);
    v[t] = x;
    mx = fmaxf(mx, x);
  }
#pragma unroll
  for (int off = 32; off >= 1; off >>= 1) mx = fmaxf(mx, __shfl_xor(mx, off, 64));
  float s = 0.f;
#pragma unroll
  for (int t = 0; t < 3; ++t) s += __expf(v[t] - mx);
#pragma unroll
  for (int off = 32; off >= 1; off >>= 1) s += __shfl_xor(s, off, 64);
  float inv = 1.0f / s;
#pragma unroll
  for (int t = 0; t < 3; ++t) {
    int j = l + 64 * t;
    out[base + j] = (j <= i) ? __expf(v[t] - mx) * inv : PADV;
  }
}

// ---------------------------------------------------------------------------
extern "C" void kernel_launch(void* const* d_in, const int* in_sizes, int n_in,
                              void* d_out, int out_size, void* d_ws, size_t ws_size,
                              hipStream_t stream) {
  const float* E  = (const float*)d_in[0];
  const float* W1 = (const float*)d_in[1];
  const float* b1 = (const float*)d_in[2];
  const float* W2 = (const float*)d_in[3];
  const float* b2 = (const float*)d_in[4];
  const float* W3 = (const float*)d_in[5];
  const float* b3 = (const float*)d_in[6];
  float* out = (float*)d_out;

  char* ws = (char*)d_ws;
  float*    A12   = (float*)(ws);               // 1,966,080 B (491520 f32)
  _Float16* W1abp = (_Float16*)(ws + 1966080);  //   491,520 B
  _Float16* W1cp  = (_Float16*)(ws + 2457600);  //   294,912 B (12-frag pad)
  _Float16* W2p   = (_Float16*)(ws + 2752512);  //    61,440 B (12-frag pad)
  float*    b1p   = (float*)(ws + 2813952);     //       640 B

  prep_pack<<<1657, 256, 0, stream>>>(W1, W2, b1, W1abp, W1cp, W2p, b1p, A12);
  prep_gemm<<<768, 256, 0, stream>>>(E, W1abp, A12);
  pair_mlp<<<624, 256, 0, stream>>>(E, A12, W1cp, W2p, b1p, b2, W3, b3, out);
  softmax_rows<<<384, 256, 0, stream>>>(out);
}

// Round 13
// 91.712 us; speedup vs baseline: 1.1357x; 1.1357x over previous
//
#include <hip/hip_runtime.h>
#include <hip/hip_bf16.h>

#define NSEQ   192
#define PADV   -1000.0f
#define NEGINF -1.0e30f

typedef _Float16 f16x8 __attribute__((ext_vector_type(8)));
typedef float    f32x4 __attribute__((ext_vector_type(4)));

#define MFMA16(a, b, c) __builtin_amdgcn_mfma_f32_16x16x32_f16((a), (b), (c), 0, 0, 0)

// ---------------------------------------------------------------------------
// prep_pack: repack weights into f16 MFMA fragment order (frag: lane l elem e
// holds M[k=(l>>4)*8+e][h=(l&15)+16q]); dense 10-frag slices (W read straight
// from global in pair_mlp -> no staging-uniformity padding needed).
// Also zeroes A12 and pads b1 -> b1p[160].
// ---------------------------------------------------------------------------
__global__ __launch_bounds__(256) void prep_pack(const float* __restrict__ W1,
                                                 const float* __restrict__ W2,
                                                 const float* __restrict__ b1,
                                                 _Float16* __restrict__ W1abp,
                                                 _Float16* __restrict__ W1cp,
                                                 _Float16* __restrict__ W2p,
                                                 float* __restrict__ b1p,
                                                 float* __restrict__ A12) {
  int idx = blockIdx.x * 256 + threadIdx.x;   // grid 1541*256 = 394496
  if (idx < 245760) { A12[idx] = 0.f; A12[245760 + idx] = 0.f; }

  if (idx < 245760) {                         // W1ab: 24 kk x 20 frags
    int e = idx & 7, l = (idx >> 3) & 63, t = idx >> 9;
    int ct = t % 20, kk = t / 20;
    int k = kk * 32 + ((l >> 4) << 3) + e;    // 0..767
    int hp = ct * 16 + (l & 15);              // 0..319
    int col = (hp < 160) ? hp : hp - 160;
    int rbase = (hp < 160) ? 0 : 768;
    float v = (col < 150) ? W1[(size_t)(rbase + k) * 150 + col] : 0.f;
    W1abp[idx] = (_Float16)v;
  } else if (idx < 368640) {                  // W1c: 24 kk x 10 frags dense
    int j = idx - 245760;
    int e = j & 7, l = (j >> 3) & 63, t = j >> 9;
    int ct = t % 10, kk = t / 10;
    int k = kk * 32 + ((l >> 4) << 3) + e;
    int h = ct * 16 + (l & 15);
    float v = (h < 150) ? W1[(size_t)(1536 + k) * 150 + h] : 0.f;
    W1cp[j] = (_Float16)v;
  } else if (idx < 394240) {                  // W2: 5 s x 10 frags dense
    int j = idx - 368640;
    int e = j & 7, l = (j >> 3) & 63, t = j >> 9;
    int ct = t % 10, s = t / 10;
    int k = s * 32 + ((l >> 4) << 3) + e;
    int h = ct * 16 + (l & 15);
    float v = (k < 150 && h < 150) ? W2[(size_t)k * 150 + h] : 0.f;
    W2p[j] = (_Float16)v;
  } else if (idx < 394400) {
    int h = idx - 394240;
    b1p[h] = (h < 150) ? b1[h] : 0.f;
  }
}

// ---------------------------------------------------------------------------
// prep_gemm: A12[1536][320] += E @ [W1a|W1b], K split 8 ways (f32 atomics).
// ---------------------------------------------------------------------------
__global__ __launch_bounds__(256) void prep_gemm(const float* __restrict__ E,
                                                 const _Float16* __restrict__ W1abp,
                                                 float* __restrict__ A12) {
  int tid = threadIdx.x;
  int w = tid >> 6, l = tid & 63, m = l & 15, kg = l >> 4;
  int mt = blockIdx.x >> 3;                   // 0..95
  int c  = blockIdx.x & 7;                    // K-chunk 0..7
  const float* ep = E + (size_t)(mt * 16 + m) * 768 + c * 96;

  f32x4 acc[5];
#pragma unroll
  for (int u = 0; u < 5; ++u) acc[u] = (f32x4){0.f, 0.f, 0.f, 0.f};

#pragma unroll
  for (int kk = 0; kk < 3; ++kk) {
    int k = kk * 32 + kg * 8;
    f32x4 x0 = *(const f32x4*)(ep + k);
    f32x4 x1 = *(const f32x4*)(ep + k + 4);
    f16x8 af;
#pragma unroll
    for (int e = 0; e < 4; ++e) { af[e] = (_Float16)x0[e]; af[e + 4] = (_Float16)x1[e]; }
    const f16x8* wp = (const f16x8*)W1abp + (size_t)(((c * 3 + kk) * 20) + w * 5) * 64 + l;
#pragma unroll
    for (int u = 0; u < 5; ++u)
      acc[u] = MFMA16(af, wp[u * 64], acc[u]);
  }
#pragma unroll
  for (int u = 0; u < 5; ++u)
#pragma unroll
    for (int r = 0; r < 4; ++r)
      atomicAdd(&A12[(size_t)(mt * 16 + kg * 4 + r) * 320 + (w * 5 + u) * 16 + m], acc[u][r]);
}

// ---------------------------------------------------------------------------
// pair_mlp r13: 16i x 8j tile (1248 blocks), 4 waves, wave w owns j-cols
// {2w, 2w+1}. BARRIER-FREE main loops: W fragments are read straight from
// global (L2/L3-resident, 1KB wave-wide dwordx4 each) into a register double
// buffer (wA/wB, depth-1 prefetch) -- no LDS staging for W, hence no
// lockstep barriers. e_i/e_j staged once in LDS (f16, XOR-swizzled); one
// __syncthreads after staging, one s_barrier before h1 overwrites eib.
// Swapped GEMM1 C1[h][i]: pack = 2 v_pk_mul_f16 per step.
// ---------------------------------------------------------------------------
__global__ __launch_bounds__(256) void pair_mlp(
    const float* __restrict__ E, const float* __restrict__ A12,
    const _Float16* __restrict__ W1cp, const _Float16* __restrict__ W2p,
    const float* __restrict__ b1p, const float* __restrict__ b2,
    const float* __restrict__ W3, const float* __restrict__ b3,
    float* __restrict__ out) {
  __shared__ alignas(16) char pool[50432];
  // phase1: eib [0,24576) 16 rows x 96 chunks(16B) XOR-swizzled;
  //         ejb [24576,36864) 8 rows x 96 chunks(16B) XOR-swizzled.
  // phase2: h1 [0,49152) = 8 slots (w*2+c) x 6144B (16 rows x 384B swizzled).
  // bw [49152,50432): b2f[160], w3f[160] f32.
  char* eib = pool;
  char* ejb = pool + 24576;

  const int tid = threadIdx.x;
  const int w = tid >> 6, l = tid & 63;
  const int m = l & 15, kg = l >> 4;
  const int jr0 = 2 * w, jr1 = 2 * w + 1;

  // XCD-aware bijective swizzle (1248 == 8*156), tri decode (16x8 tiles)
  int bid = blockIdx.x;
  int blk = (bid & 7) * 156 + (bid >> 3);
  int b = blk / 156, r0 = blk - b * 156;
  int it = (int)((sqrtf(4.f * (float)r0 + 1.f) - 1.f) * 0.5f);
  while (it * it + it > r0) --it;
  while ((it + 1) * (it + 1) + (it + 1) <= r0) ++it;
  int jt = r0 - it * it - it;                 // 0..2it+1

  const int ibase = b * NSEQ + it * 16;
  const int jbase = b * NSEQ + jt * 8;

  // ---- stage e_i (16 rows) + e_j (8 rows) as f16, chunk-XOR swizzled ----
#pragma unroll
  for (int q = 0; q < 9; ++q) {
    int t = tid + 256 * q;                    // 0..2303
    int isI = (t < 1536);
    int tt = isI ? t : t - 1536;
    int r = tt / 96, d = tt - (tt / 96) * 96;
    int sc = d ^ (r & 7);
    const float* src = E + (size_t)((isI ? ibase : jbase) + r) * 768 + sc * 8;
    f32x4 a0 = *(const f32x4*)(src);
    f32x4 a1 = *(const f32x4*)(src + 4);
    f16x8 v;
#pragma unroll
    for (int e = 0; e < 4; ++e) { v[e] = (_Float16)a0[e]; v[e + 4] = (_Float16)a1[e]; }
    *(f16x8*)((isI ? eib : ejb) + r * 1536 + d * 16) = v;
  }

  // ---- stage b2/W3 (padded) ----
  if (tid < 160) {
    float* bwf = (float*)(pool + 49152);
    bwf[tid]       = (tid < 150) ? b2[tid] : 0.f;
    bwf[160 + tid] = (tid < 150) ? W3[tid] : 0.f;
  }
  float b3v = b3[0];

  // ---- acc1 init: C1[h = ct*16+kg*4+r][i = m] = A1[i][h]+A2[j][h]+b1[h] ----
  f32x4 acc1[10][2];
#pragma unroll
  for (int ct = 0; ct < 10; ++ct) {
    f32x4 a1v = *(const f32x4*)(A12 + (size_t)(ibase + m) * 320 + ct * 16 + kg * 4);
    f32x4 b1v = *(const f32x4*)(b1p + ct * 16 + kg * 4);
#pragma unroll
    for (int pt = 0; pt < 2; ++pt) {
      f32x4 a2v = *(const f32x4*)(A12 + (size_t)(jbase + jr0 + pt) * 320 + 160 + ct * 16 + kg * 4);
      acc1[ct][pt] = a1v + a2v + b1v;
    }
  }

  __syncthreads();   // the ONLY full-block drain: e-tiles + bw resident

  // ---- GEMM1: 24 K=32 steps, barrier-free, W in register dbuf ----
  f16x8 wA[10], wB[10];
#pragma unroll
  for (int ct = 0; ct < 10; ++ct)
    wA[ct] = *(const f16x8*)(W1cp + (size_t)ct * 512 + l * 8);

  auto step1 = [&](int t, f16x8* cur, f16x8* nxt) {
    if (t < 23) {
#pragma unroll
      for (int ct = 0; ct < 10; ++ct)
        nxt[ct] = *(const f16x8*)(W1cp + ((size_t)(t + 1) * 10 + ct) * 512 + l * 8);
    }
    int cb = t * 4 + kg;
    f16x8 eiv = *(const f16x8*)(eib + m * 1536 + ((cb ^ (m & 7)) << 4));
    f16x8 ej0 = *(const f16x8*)(ejb + jr0 * 1536 + ((cb ^ (jr0 & 7)) << 4));
    f16x8 ej1 = *(const f16x8*)(ejb + jr1 * 1536 + ((cb ^ (jr1 & 7)) << 4));
    f16x8 pf0 = eiv * ej0;                    // v_pk_mul_f16
    f16x8 pf1 = eiv * ej1;
#pragma unroll
    for (int ct = 0; ct < 10; ++ct) {
      acc1[ct][0] = MFMA16(cur[ct], pf0, acc1[ct][0]);
      acc1[ct][1] = MFMA16(cur[ct], pf1, acc1[ct][1]);
    }
  };
  for (int t = 0; t < 24; t += 2) {
    step1(t, wA, wB);
    step1(t + 1, wB, wA);
  }

  // ---- issue W2 slice 0 prefetch, then barrier (h1 overwrites eib) ----
  f16x8 vA[10], vB[10];
#pragma unroll
  for (int ct = 0; ct < 10; ++ct)
    vA[ct] = *(const f16x8*)(W2p + (size_t)ct * 512 + l * 8);

  asm volatile("s_waitcnt lgkmcnt(0)" ::: "memory");
  __builtin_amdgcn_s_barrier();               // all eib/ejb reads complete

  // ---- h1 (relu, f16) -> wave-private slots; then barrier-free GEMM2 ----
  auto write_h1 = [&](int c) {
    char* hbp = pool + (w * 2 + c) * 6144;
#pragma unroll
    for (int ct = 0; ct < 10; ++ct) {
      union { _Float16 h[4]; unsigned u[2]; } cv;
      cv.h[0] = (_Float16)fmaxf(acc1[ct][c][0], 0.f);
      cv.h[1] = (_Float16)fmaxf(acc1[ct][c][1], 0.f);
      cv.h[2] = (_Float16)fmaxf(acc1[ct][c][2], 0.f);
      cv.h[3] = (_Float16)fmaxf(acc1[ct][c][3], 0.f);
      int cc = (2 * ct + (kg >> 1)) ^ (m & 7);
      char* dst = hbp + m * 384 + cc * 16 + (kg & 1) * 8;
      *(unsigned*)(dst)     = cv.u[0];
      *(unsigned*)(dst + 4) = cv.u[1];
    }
  };
  write_h1(0);
  write_h1(1);

  f32x4 acc2[10][2];
#pragma unroll
  for (int ct = 0; ct < 10; ++ct) {
    acc2[ct][0] = (f32x4){0.f, 0.f, 0.f, 0.f};
    acc2[ct][1] = (f32x4){0.f, 0.f, 0.f, 0.f};
  }

#pragma unroll
  for (int s = 0; s < 5; ++s) {
    f16x8* cur = (s & 1) ? vB : vA;
    f16x8* nxt = (s & 1) ? vA : vB;
    if (s < 4) {
#pragma unroll
      for (int ct = 0; ct < 10; ++ct)
        nxt[ct] = *(const f16x8*)(W2p + ((size_t)(s + 1) * 10 + ct) * 512 + l * 8);
    }
    f16x8 hf0 = *(const f16x8*)(pool + (w * 2 + 0) * 6144 + m * 384 +
                                (((4 * s + kg) ^ (m & 7)) << 4));
    f16x8 hf1 = *(const f16x8*)(pool + (w * 2 + 1) * 6144 + m * 384 +
                                (((4 * s + kg) ^ (m & 7)) << 4));
#pragma unroll
    for (int ct = 0; ct < 10; ++ct) {
      acc2[ct][0] = MFMA16(cur[ct], hf0, acc2[ct][0]);
      acc2[ct][1] = MFMA16(cur[ct], hf1, acc2[ct][1]);
    }
  }

  // ---- epilogue: s = relu(h2+b2)@W3 + b3; reduce over kg; store ----
  const float* bwp = (const float*)(pool + 49152);
#pragma unroll
  for (int c = 0; c < 2; ++c) {
    float sum = 0.f;
#pragma unroll
    for (int ct = 0; ct < 10; ++ct) {
      f32x4 b2q = *(const f32x4*)(bwp + ct * 16 + kg * 4);
      f32x4 w3q = *(const f32x4*)(bwp + 160 + ct * 16 + kg * 4);
#pragma unroll
      for (int r2 = 0; r2 < 4; ++r2)
        sum += fmaxf(acc2[ct][c][r2] + b2q[r2], 0.f) * w3q[r2];
    }
    sum += __shfl_xor(sum, 16, 64);
    sum += __shfl_xor(sum, 32, 64);
    if (kg == 0) {
      int il = it * 16 + m;
      int jl = jt * 8 + 2 * w + c;
      if (jl < il)
        out[(size_t)(b * NSEQ + il) * NSEQ + jl] = sum + b3v;
    }
  }
}

// ---------------------------------------------------------------------------
// softmax: 4 (b,i)-rows per block, one wave each.
// ---------------------------------------------------------------------------
__global__ __launch_bounds__(256) void softmax_rows(float* __restrict__ out) {
  int w = threadIdx.x >> 6, l = threadIdx.x & 63;
  int blk = blockIdx.x * 4 + w;   // 0..1535 = b*192+i
  int i = blk % NSEQ;
  size_t base = (size_t)blk * NSEQ;
  float v[3];
  float mx = NEGINF;
#pragma unroll
  for (int t = 0; t < 3; ++t) {
    int j = l + 64 * t;
    float x = (j < i) ? out[base + j] : (j == i ? 0.f : NEGINF);
    v[t] = x;
    mx = fmaxf(mx, x);
  }
#pragma unroll
  for (int off = 32; off >= 1; off >>= 1) mx = fmaxf(mx, __shfl_xor(mx, off, 64));
  float s = 0.f;
#pragma unroll
  for (int t = 0; t < 3; ++t) s += __expf(v[t] - mx);
#pragma unroll
  for (int off = 32; off >= 1; off >>= 1) s += __shfl_xor(s, off, 64);
  float inv = 1.0f / s;
#pragma unroll
  for (int t = 0; t < 3; ++t) {
    int j = l + 64 * t;
    out[base + j] = (j <= i) ? __expf(v[t] - mx) * inv : PADV;
  }
}

// ---------------------------------------------------------------------------
extern "C" void kernel_launch(void* const* d_in, const int* in_sizes, int n_in,
                              void* d_out, int out_size, void* d_ws, size_t ws_size,
                              hipStream_t stream) {
  const float* E  = (const float*)d_in[0];
  const float* W1 = (const float*)d_in[1];
  const float* b1 = (const float*)d_in[2];
  const float* W2 = (const float*)d_in[3];
  const float* b2 = (const float*)d_in[4];
  const float* W3 = (const float*)d_in[5];
  const float* b3 = (const float*)d_in[6];
  float* out = (float*)d_out;

  char* ws = (char*)d_ws;
  float*    A12   = (float*)(ws);               // 1,966,080 B (491520 f32)
  _Float16* W1abp = (_Float16*)(ws + 1966080);  //   491,520 B
  _Float16* W1cp  = (_Float16*)(ws + 2457600);  //   245,760 B (dense 10-frag)
  _Float16* W2p   = (_Float16*)(ws + 2703360);  //    51,200 B (dense 10-frag)
  float*    b1p   = (float*)(ws + 2754560);     //       640 B

  prep_pack<<<1541, 256, 0, stream>>>(W1, W2, b1, W1abp, W1cp, W2p, b1p, A12);
  prep_gemm<<<768, 256, 0, stream>>>(E, W1abp, A12);
  pair_mlp<<<1248, 256, 0, stream>>>(E, A12, W1cp, W2p, b1p, b2, W3, b3, out);
  softmax_rows<<<384, 256, 0, stream>>>(out);
}